// Round 2
// baseline (123.234 us; speedup 1.0000x reference)
//
#include <hip/hip_runtime.h>
#include <math.h>

// CapsuleLayer dynamic routing, fully fused: one block per batch element.
// B=256, O=10, U=36, S=32, E=16, F=8, N=1152, 3 routing iterations.
//
// Key identity: u[o,n,e] = sum_f W[o,u(n),e,f] * x[n,f] is never materialized.
//   v_pre[o,e]  = sum_{u,f} W[o,u,e,f] * cx[o,u,f],  cx[o,u,f] = sum_s c[o,n]*x[n,f]
//   b[o,n]     += sum_f x[n,f] * wv[o,u,f],          wv[o,u,f] = sum_e W[o,u,e,f]*v[o,e]
//
// LDS swizzles: u-stride is 32 rows -> 32*pitch = 0 mod 32 banks for ANY pitch,
// so row-major tiles are cursed; rotate slots by u instead:
//   x row n, 16B half h  -> word u*256 + (((s<<1)+h+u)&63)*4   (b128-aligned)
//   c[o][n]              -> word o*1152 + u*32 + ((s+u)&31)

namespace {

constexpr int kO = 10;         // out capsules
constexpr int kU = 36;         // unique in-capsules
constexpr int kS = 32;         // sharing per unique
constexpr int kE = 16;         // out features
constexpr int kF = 8;          // in features
constexpr int kN = kU * kS;    // 1152
constexpr int kIters = 3;
constexpr int kThreads = 576;  // 9 waves; 1152/576 = exactly 2 rows/thread
constexpr int kRows = 2;

__launch_bounds__(kThreads, 1)
__global__ void caps_routing_kernel(const float* __restrict__ xg,
                                    const float* __restrict__ Wg,
                                    float* __restrict__ outg) {
    __shared__ float s_x[kN * kF];        // 36864 B, swizzled (see header comment)
    __shared__ float s_c[kO * kN];        // 46080 B, swizzled
    __shared__ float s_cx[kO * kU * kF];  // 11520 B, [(o*36+u)*8 + f]
    __shared__ float s_wv[kO * kU * kF];  // 11520 B
    __shared__ float s_v[kO * kE];        //   640 B
    // total ~104 KB < 160 KB

    const int t = threadIdx.x;
    const int b = blockIdx.x;

    float xr[kRows][kF];   // this thread's x rows (registers)
    float br[kRows][kO];   // routing logits b[o,n] for owned rows (registers)
    int   ru[kRows], rrot[kRows];

    // ---- load x rows: global (coalesced b128) -> regs + swizzled LDS ----
#pragma unroll
    for (int k = 0; k < kRows; ++k) {
        const int n = t + k * kThreads;
        const int u = n >> 5;
        const int s = n & 31;
        ru[k]   = u;
        rrot[k] = (s + u) & 31;
        const float4* src =
            reinterpret_cast<const float4*>(xg + ((size_t)b * kN + n) * kF);
        const float4 a0 = src[0];
        const float4 a1 = src[1];
        xr[k][0] = a0.x; xr[k][1] = a0.y; xr[k][2] = a0.z; xr[k][3] = a0.w;
        xr[k][4] = a1.x; xr[k][5] = a1.y; xr[k][6] = a1.z; xr[k][7] = a1.w;
        const int sl0 = ((s << 1) + 0 + u) & 63;
        const int sl1 = ((s << 1) + 1 + u) & 63;
        *reinterpret_cast<float4*>(&s_x[u * 256 + sl0 * 4]) = a0;
        *reinterpret_cast<float4*>(&s_x[u * 256 + sl1 * 4]) = a1;
#pragma unroll
        for (int o = 0; o < kO; ++o) br[k][o] = 0.f;
    }
    // initial c = softmax(0) over O = 1/10 everywhere
    for (int i = t; i < kO * kN; i += kThreads) s_c[i] = 0.1f;
    __syncthreads();

    for (int it = 0; it <= kIters; ++it) {
        // ---- cx[o][u][f] = sum_s c[o][n]*x[n][f]; thread = (o-pair, u), 180 active
        if (t < (kO / 2) * kU) {
            const int op = t / kU;
            const int u  = t - op * kU;
            const int o0 = op * 2, o1 = o0 + 1;
            float a0[kF] = {0, 0, 0, 0, 0, 0, 0, 0};
            float a1[kF] = {0, 0, 0, 0, 0, 0, 0, 0};
#pragma unroll 8
            for (int s = 0; s < kS; ++s) {
                const int rot = (s + u) & 31;
                const int sl0 = ((s << 1) + 0 + u) & 63;
                const int sl1 = ((s << 1) + 1 + u) & 63;
                const float4 xa = *reinterpret_cast<const float4*>(&s_x[u * 256 + sl0 * 4]);
                const float4 xb = *reinterpret_cast<const float4*>(&s_x[u * 256 + sl1 * 4]);
                const float c0 = s_c[o0 * kN + u * 32 + rot];
                const float c1 = s_c[o1 * kN + u * 32 + rot];
                a0[0] += c0 * xa.x; a0[1] += c0 * xa.y; a0[2] += c0 * xa.z; a0[3] += c0 * xa.w;
                a0[4] += c0 * xb.x; a0[5] += c0 * xb.y; a0[6] += c0 * xb.z; a0[7] += c0 * xb.w;
                a1[0] += c1 * xa.x; a1[1] += c1 * xa.y; a1[2] += c1 * xa.z; a1[3] += c1 * xa.w;
                a1[4] += c1 * xb.x; a1[5] += c1 * xb.y; a1[6] += c1 * xb.z; a1[7] += c1 * xb.w;
            }
            float4* d0 = reinterpret_cast<float4*>(&s_cx[(o0 * kU + u) * kF]);
            d0[0] = make_float4(a0[0], a0[1], a0[2], a0[3]);
            d0[1] = make_float4(a0[4], a0[5], a0[6], a0[7]);
            float4* d1 = reinterpret_cast<float4*>(&s_cx[(o1 * kU + u) * kF]);
            d1[0] = make_float4(a1[0], a1[1], a1[2], a1[3]);
            d1[1] = make_float4(a1[4], a1[5], a1[6], a1[7]);
        }
        __syncthreads();

        // ---- v_pre[o][e] = sum_{u,f} W[o][u][e][f]*cx[o][u][f]; thread=(o,e), 160 active
        if (t < kO * kE) {
            const int o = t / kE;
            const int e = t - o * kE;
            float acc = 0.f;
#pragma unroll 6
            for (int u = 0; u < kU; ++u) {
                const float4* wp =
                    reinterpret_cast<const float4*>(Wg + ((size_t)(o * kU + u) * kE + e) * kF);
                const float4 w0 = wp[0];
                const float4 w1 = wp[1];
                const float4* cp = reinterpret_cast<const float4*>(&s_cx[(o * kU + u) * kF]);
                const float4 c0 = cp[0];
                const float4 c1 = cp[1];
                acc += w0.x * c0.x + w0.y * c0.y + w0.z * c0.z + w0.w * c0.w;
                acc += w1.x * c1.x + w1.y * c1.y + w1.z * c1.z + w1.w * c1.w;
            }
            s_v[t] = acc;
        }
        __syncthreads();

        // ---- squash: v = v_pre * |v_pre| / (1+|v_pre|^2); final pass writes output
        if (t < kO) {
            float n2 = 0.f;
#pragma unroll
            for (int e = 0; e < kE; ++e) {
                const float z = s_v[t * kE + e];
                n2 += z * z;
            }
            const float scale = sqrtf(n2) / (1.f + n2);
            if (it == kIters) {
#pragma unroll
                for (int e = 0; e < kE; ++e)
                    outg[((size_t)b * kO + t) * kE + e] = s_v[t * kE + e] * scale;
            } else {
#pragma unroll
                for (int e = 0; e < kE; ++e) s_v[t * kE + e] *= scale;
            }
        }
        if (it == kIters) break;
        __syncthreads();

        // ---- wv[o][u][f] = sum_e W[o][u][e][f]*v[o][e]; thread=(o,u), 360 active
        if (t < kO * kU) {
            const int o = t / kU;
            const int u = t - o * kU;
            float4 acc0 = make_float4(0.f, 0.f, 0.f, 0.f);
            float4 acc1 = make_float4(0.f, 0.f, 0.f, 0.f);
#pragma unroll 4
            for (int e = 0; e < kE; ++e) {
                const float ve = s_v[o * kE + e];  // broadcast
                const float4* wp =
                    reinterpret_cast<const float4*>(Wg + ((size_t)(o * kU + u) * kE + e) * kF);
                const float4 w0 = wp[0];
                const float4 w1 = wp[1];
                acc0.x += ve * w0.x; acc0.y += ve * w0.y; acc0.z += ve * w0.z; acc0.w += ve * w0.w;
                acc1.x += ve * w1.x; acc1.y += ve * w1.y; acc1.z += ve * w1.z; acc1.w += ve * w1.w;
            }
            float4* d = reinterpret_cast<float4*>(&s_wv[(o * kU + u) * kF]);
            d[0] = acc0;
            d[1] = acc1;
        }
        __syncthreads();

        // ---- b[o,n] += x[n,:].wv[o,u,:]; softmax over o (thread-local); write c
#pragma unroll
        for (int k = 0; k < kRows; ++k) {
            const int u   = ru[k];
            const int rot = rrot[k];
            float mx = -3.4e38f;
#pragma unroll
            for (int o = 0; o < kO; ++o) {
                const float4* wp = reinterpret_cast<const float4*>(&s_wv[(o * kU + u) * kF]);
                const float4 w0 = wp[0];  // broadcast across the 32-lane u-run
                const float4 w1 = wp[1];
                br[k][o] += w0.x * xr[k][0] + w0.y * xr[k][1] + w0.z * xr[k][2] + w0.w * xr[k][3]
                          + w1.x * xr[k][4] + w1.y * xr[k][5] + w1.z * xr[k][6] + w1.w * xr[k][7];
                mx = fmaxf(mx, br[k][o]);
            }
            float ex[kO];
            float sum = 0.f;
#pragma unroll
            for (int o = 0; o < kO; ++o) {
                ex[o] = __expf(br[k][o] - mx);
                sum += ex[o];
            }
            const float inv = 1.f / sum;
#pragma unroll
            for (int o = 0; o < kO; ++o) s_c[o * kN + u * 32 + rot] = ex[o] * inv;
        }
        __syncthreads();
    }
}

}  // namespace

extern "C" void kernel_launch(void* const* d_in, const int* in_sizes, int n_in,
                              void* d_out, int out_size, void* d_ws, size_t ws_size,
                              hipStream_t stream) {
    const float* x = (const float*)d_in[0];  // (B, 1152, 8) fp32
    const float* W = (const float*)d_in[1];  // (10, 36, 16, 8) fp32
    float* out = (float*)d_out;              // (B, 10, 16) fp32

    const int batch = in_sizes[0] / (kN * kF);  // 256
    caps_routing_kernel<<<dim3(batch), dim3(kThreads), 0, stream>>>(x, W, out);
}

// Round 3
// 110.862 us; speedup vs baseline: 1.1116x; 1.1116x over previous
//
#include <hip/hip_runtime.h>
#include <math.h>

// CapsuleLayer dynamic routing, fully fused: one block per batch element.
// B=256, O=10, U=36, S=32, E=16, F=8, N=1152, 3 routing iterations.
//
// u_hat is never materialized:
//   v_pre[o,e]  = sum_{u,f} W[o,u,e,f] * cx[o,u,f],  cx[o,u,f] = sum_s c[o,n]*x[n,f]
//   b[o,n]     += sum_f x[n,f] * wv[o,u,f],          wv[o,u,f] = sum_e W[o,u,e,f]*v[o,e]
//
// Round-3 restructure (vs round 2, 72us @ VALUBusy 14%): every phase >=360 of
// 576 threads, barriers 24->14, iteration-0 cx replaced by prologue shuffle-
// reduced sx (c0 is uniform 0.1 so cx0 = 0.1*sum_s x), squash folded into wv
// (redundant per-thread norm from v_pre partials), s_cx/s_wv pitch 12 to break
// the 8-word-stride b128 write conflict.
//
// LDS swizzles: u-stride is 32 rows -> 32*pitch = 0 mod 32 banks for any pitch:
//   x row n, 16B half h  -> word u*256 + (((s<<1)+h+u)&63)*4
//   c[o][n]              -> word o*1152 + u*32 + ((s+u)&31)

namespace {

constexpr int kO = 10;
constexpr int kU = 36;
constexpr int kS = 32;
constexpr int kE = 16;
constexpr int kF = 8;
constexpr int kN = kU * kS;    // 1152
constexpr int kIters = 3;
constexpr int kThreads = 576;  // 9 waves
constexpr int kRows = 2;
constexpr int kPitch = 12;     // padded (o,u)-row pitch for s_cx/s_wv

__launch_bounds__(kThreads, 3)  // 3 waves/SIMD min -> VGPR <= 170 so 9-wave block fits
__global__ void caps_routing_kernel(const float* __restrict__ xg,
                                    const float* __restrict__ Wg,
                                    float* __restrict__ outg) {
    __shared__ float s_x[kN * kF];             // 36.9 KB, swizzled
    __shared__ float s_c[kO * kN];             // 46.1 KB, swizzled
    __shared__ float s_cx[kO * kU * kPitch];   // 17.3 KB
    __shared__ float s_wv[kO * kU * kPitch];   // 17.3 KB
    __shared__ float s_vp[kO * kE * 3];        //  1.9 KB (3 u-chunk partials)
    __shared__ float s_sx[kU * kF];            //  1.2 KB (sum_s x, for it=0)
    // total ~121 KB

    const int t = threadIdx.x;
    const int b = blockIdx.x;

    float xr[kRows][kF];   // this thread's x rows
    float br[kRows][kO];   // routing logits for owned rows
    int   ru[kRows], rrot[kRows];

    // ---- prologue: load x rows -> regs + swizzled LDS; half-wave reduce sx ----
#pragma unroll
    for (int k = 0; k < kRows; ++k) {
        const int n = t + k * kThreads;
        const int u = n >> 5;
        const int s = n & 31;
        ru[k]   = u;
        rrot[k] = (s + u) & 31;
        const float4* src =
            reinterpret_cast<const float4*>(xg + ((size_t)b * kN + n) * kF);
        const float4 a0 = src[0];
        const float4 a1 = src[1];
        xr[k][0] = a0.x; xr[k][1] = a0.y; xr[k][2] = a0.z; xr[k][3] = a0.w;
        xr[k][4] = a1.x; xr[k][5] = a1.y; xr[k][6] = a1.z; xr[k][7] = a1.w;
        const int sl0 = ((s << 1) + 0 + u) & 63;
        const int sl1 = ((s << 1) + 1 + u) & 63;
        *reinterpret_cast<float4*>(&s_x[u * 256 + sl0 * 4]) = a0;
        *reinterpret_cast<float4*>(&s_x[u * 256 + sl1 * 4]) = a1;

        // sx[u][f] = sum_s x[u,s,f]: the 32 rows of u are exactly one half-wave
        float r[kF];
#pragma unroll
        for (int f = 0; f < kF; ++f) r[f] = xr[k][f];
#pragma unroll
        for (int m = 1; m <= 16; m <<= 1) {
#pragma unroll
            for (int f = 0; f < kF; ++f) r[f] += __shfl_xor(r[f], m);
        }
        if (s == 0) {
            *reinterpret_cast<float4*>(&s_sx[u * kF + 0]) =
                make_float4(r[0], r[1], r[2], r[3]);
            *reinterpret_cast<float4*>(&s_sx[u * kF + 4]) =
                make_float4(r[4], r[5], r[6], r[7]);
        }
#pragma unroll
        for (int o = 0; o < kO; ++o) br[k][o] = 0.f;
    }
    __syncthreads();

    for (int it = 0; it <= kIters; ++it) {
        // ---- cx[o][u][f] = sum_s c[o][n]*x[n][f]; thread=(o,u), 360 active ----
        // (skipped at it=0: c is uniform 0.1, folded into v_pre via s_sx)
        if (it > 0) {
            if (t < kO * kU) {
                const int o = t / kU;
                const int u = t - o * kU;
                float a0[kF] = {0, 0, 0, 0, 0, 0, 0, 0};
#pragma unroll 8
                for (int s = 0; s < kS; ++s) {
                    const int rot = (s + u) & 31;
                    const int sl0 = ((s << 1) + 0 + u) & 63;
                    const int sl1 = ((s << 1) + 1 + u) & 63;
                    const float4 xa =
                        *reinterpret_cast<const float4*>(&s_x[u * 256 + sl0 * 4]);
                    const float4 xb =
                        *reinterpret_cast<const float4*>(&s_x[u * 256 + sl1 * 4]);
                    const float c0 = s_c[o * kN + u * 32 + rot];
                    a0[0] += c0 * xa.x; a0[1] += c0 * xa.y;
                    a0[2] += c0 * xa.z; a0[3] += c0 * xa.w;
                    a0[4] += c0 * xb.x; a0[5] += c0 * xb.y;
                    a0[6] += c0 * xb.z; a0[7] += c0 * xb.w;
                }
                float4* d = reinterpret_cast<float4*>(&s_cx[(o * kU + u) * kPitch]);
                d[0] = make_float4(a0[0], a0[1], a0[2], a0[3]);
                d[1] = make_float4(a0[4], a0[5], a0[6], a0[7]);
            }
            __syncthreads();
        }

        // ---- v_pre partials: thread=(o,e,uc), 480 active; 12 u's each ----
        if (t < kO * kE * 3) {
            const int o  = t / (kE * 3);
            const int r  = t - o * (kE * 3);
            const int e  = r / 3;
            const int uc = r - e * 3;
            const int u0 = uc * 12;
            float acc = 0.f;
#pragma unroll 6
            for (int ui = 0; ui < 12; ++ui) {
                const int u = u0 + ui;
                const float4* wp = reinterpret_cast<const float4*>(
                    Wg + ((size_t)(o * kU + u) * kE + e) * kF);
                const float4 w0 = wp[0];
                const float4 w1 = wp[1];
                float4 c0, c1;
                if (it == 0) {
                    const float4* cp = reinterpret_cast<const float4*>(&s_sx[u * kF]);
                    c0 = cp[0]; c1 = cp[1];
                } else {
                    const float4* cp =
                        reinterpret_cast<const float4*>(&s_cx[(o * kU + u) * kPitch]);
                    c0 = cp[0]; c1 = cp[1];
                }
                acc += w0.x * c0.x + w0.y * c0.y + w0.z * c0.z + w0.w * c0.w;
                acc += w1.x * c1.x + w1.y * c1.y + w1.z * c1.z + w1.w * c1.w;
            }
            if (it == 0) acc *= 0.1f;
            s_vp[(o * kE + e) * 3 + uc] = acc;
        }
        __syncthreads();

        // ---- final pass: squash + store output, done ----
        if (it == kIters) {
            if (t < kO * kE) {
                const float vsum = s_vp[t * 3 + 0] + s_vp[t * 3 + 1] + s_vp[t * 3 + 2];
                float n2 = vsum * vsum;
#pragma unroll
                for (int m = 1; m <= 8; m <<= 1) n2 += __shfl_xor(n2, m);
                const float scale = sqrtf(n2) / (1.f + n2);
                outg[(size_t)b * kO * kE + t] = vsum * scale;
            }
            break;
        }

        // ---- wv[o][u][f] = sum_e W[o][u][e][f]*v[o][e]; thread=(o,u), 360 active
        // squash folded in: each thread rebuilds v from the 480 partials (broadcast reads)
        if (t < kO * kU) {
            const int o = t / kU;
            const int u = t - o * kU;
            float vs[kE];
            float n2 = 0.f;
#pragma unroll
            for (int e = 0; e < kE; ++e) {
                const int base = (o * kE + e) * 3;
                const float v0 = s_vp[base + 0] + s_vp[base + 1] + s_vp[base + 2];
                vs[e] = v0;
                n2 += v0 * v0;
            }
            const float scale = sqrtf(n2) / (1.f + n2);
            float4 acc0 = make_float4(0.f, 0.f, 0.f, 0.f);
            float4 acc1 = make_float4(0.f, 0.f, 0.f, 0.f);
#pragma unroll
            for (int e = 0; e < kE; ++e) {
                const float ve = vs[e] * scale;
                const float4* wp = reinterpret_cast<const float4*>(
                    Wg + ((size_t)(o * kU + u) * kE + e) * kF);
                const float4 w0 = wp[0];
                const float4 w1 = wp[1];
                acc0.x += ve * w0.x; acc0.y += ve * w0.y;
                acc0.z += ve * w0.z; acc0.w += ve * w0.w;
                acc1.x += ve * w1.x; acc1.y += ve * w1.y;
                acc1.z += ve * w1.z; acc1.w += ve * w1.w;
            }
            float4* d = reinterpret_cast<float4*>(&s_wv[(o * kU + u) * kPitch]);
            d[0] = acc0;
            d[1] = acc1;
        }
        __syncthreads();

        // ---- b[o,n] += x[n,:].wv[o,u,:]; thread-local softmax over o; write c ----
#pragma unroll
        for (int k = 0; k < kRows; ++k) {
            const int u   = ru[k];
            const int rot = rrot[k];
            float mx = -3.4e38f;
#pragma unroll
            for (int o = 0; o < kO; ++o) {
                const float4* wp =
                    reinterpret_cast<const float4*>(&s_wv[(o * kU + u) * kPitch]);
                const float4 w0 = wp[0];  // broadcast across the half-wave (same u)
                const float4 w1 = wp[1];
                br[k][o] += w0.x * xr[k][0] + w0.y * xr[k][1] + w0.z * xr[k][2] + w0.w * xr[k][3]
                          + w1.x * xr[k][4] + w1.y * xr[k][5] + w1.z * xr[k][6] + w1.w * xr[k][7];
                mx = fmaxf(mx, br[k][o]);
            }
            float ex[kO];
            float sum = 0.f;
#pragma unroll
            for (int o = 0; o < kO; ++o) {
                ex[o] = __expf(br[k][o] - mx);
                sum += ex[o];
            }
            const float inv = 1.f / sum;
#pragma unroll
            for (int o = 0; o < kO; ++o) s_c[o * kN + u * 32 + rot] = ex[o] * inv;
        }
        __syncthreads();
    }
}

}  // namespace

extern "C" void kernel_launch(void* const* d_in, const int* in_sizes, int n_in,
                              void* d_out, int out_size, void* d_ws, size_t ws_size,
                              hipStream_t stream) {
    const float* x = (const float*)d_in[0];  // (B, 1152, 8) fp32
    const float* W = (const float*)d_in[1];  // (10, 36, 16, 8) fp32
    float* out = (float*)d_out;              // (B, 10, 16) fp32

    const int batch = in_sizes[0] / (kN * kF);  // 256
    caps_routing_kernel<<<dim3(batch), dim3(kThreads), 0, stream>>>(x, W, out);
}